// Round 1
// baseline (186.606 us; speedup 1.0000x reference)
//
#include <hip/hip_runtime.h>
#include <hip/hip_bf16.h>

#define E_ 8
#define B_ 8
#define S_ 2048
#define D_ 512
#define R_ 128
#define M_TOT (B_ * S_)   // 16384

typedef __attribute__((ext_vector_type(8))) short bf16x8;
typedef __attribute__((ext_vector_type(4))) float f32x4;

__device__ __forceinline__ void gload_lds16(void* lds, const void* g) {
  __builtin_amdgcn_global_load_lds(
      (const __attribute__((address_space(1))) void*)g,
      (__attribute__((address_space(3))) void*)lds, 16, 0, 0);
}

// ---------------------------------------------------------------------------
// Kernel 1: rotation part of W[e] = proj_w[e] @ Rm[e].
// All Givens planes are (0, k+1), applied as column ops; applying them to
// proj_w directly gives W. Per row o: sequential recurrence over k.
// Produces W columns 0..128 in bf16, row-major [o][d].
// ---------------------------------------------------------------------------
__global__ void build_w_rot(const float* __restrict__ theta,
                            const float* __restrict__ proj_w,
                            __hip_bfloat16* __restrict__ Wb) {
  int e = blockIdx.x;
  int o = threadIdx.x;  // 0..511
  __shared__ float cs[R_], ss[R_];
  if (o < R_) {
    float a = tanhf(theta[e * R_ + o]) * 0.1f;
    cs[o] = cosf(a);
    ss[o] = sinf(a);
  }
  __syncthreads();
  const float* P = proj_w + ((size_t)e * D_ + o) * D_;
  __hip_bfloat16* W = Wb + ((size_t)e * D_ + o) * D_;
  float u = P[0];
  for (int k = 0; k < R_; ++k) {
    float pj = P[k + 1];
    W[k + 1] = __float2bfloat16(cs[k] * pj - ss[k] * u);
    u = cs[k] * u + ss[k] * pj;
  }
  W[0] = __float2bfloat16(u);
}

// ---------------------------------------------------------------------------
// Kernel 2: untouched columns d = 129..511 of W are proj_w columns. bf16 copy.
// ---------------------------------------------------------------------------
__global__ void conv_tail(const float* __restrict__ pw,
                          __hip_bfloat16* __restrict__ Wb) {
  int i = blockIdx.x * blockDim.x + threadIdx.x;  // over E*D*D = 2M
  int d = i & (D_ - 1);
  if (d > R_) Wb[i] = __float2bfloat16(pw[i]);
}

// ---------------------------------------------------------------------------
// Kernel 3: x f32 -> bf16, float4 vectorized.
// ---------------------------------------------------------------------------
__global__ void conv_x(const float* __restrict__ x,
                       __hip_bfloat16* __restrict__ xb) {
  int i = blockIdx.x * blockDim.x + threadIdx.x;  // over (B*S*D)/4
  float4 v = ((const float4*)x)[i];
  union { short4 s; __hip_bfloat16 h[4]; } u;
  u.h[0] = __float2bfloat16(v.x);
  u.h[1] = __float2bfloat16(v.y);
  u.h[2] = __float2bfloat16(v.z);
  u.h[3] = __float2bfloat16(v.w);
  ((short4*)xb)[i] = u.s;
}

// ---------------------------------------------------------------------------
// Kernel 4: out[e] = Xb @ Wb[e]^T   (NT GEMM, both operands K-contiguous)
// M=16384, N=512, K=512 per e.  128x128 tile, BK=64, 4 waves (2x2),
// mfma_f32_16x16x32_bf16, 4x4 frags/wave, global_load_lds(16B) staging.
// ---------------------------------------------------------------------------
__global__ __launch_bounds__(256) void gemm_xw(
    const __hip_bfloat16* __restrict__ Xb,   // [M_TOT][512]
    const __hip_bfloat16* __restrict__ Wb,   // [E][512][512]  rows=o, cols=d
    float* __restrict__ out)                 // [E][M_TOT][512]
{
  constexpr int BM = 128, BN = 128, BK = 64;
  constexpr int K = D_, N = D_;
  __shared__ __align__(16) __hip_bfloat16 As[BM * BK];  // 16 KB
  __shared__ __align__(16) __hip_bfloat16 Bs[BN * BK];  // 16 KB

  int bx = blockIdx.x;
  int e = bx >> 9;        // 512 blocks per e
  int rem = bx & 511;
  int mt = rem >> 2;      // 128 m-tiles
  int nt = rem & 3;       // 4 n-tiles

  int tid = threadIdx.x;
  int wave = tid >> 6, lane = tid & 63;
  int lr = lane & 15, lk = lane >> 4;
  int wm = wave >> 1, wn = wave & 1;

  const __hip_bfloat16* Ag = Xb + (size_t)(mt * BM) * K;
  const __hip_bfloat16* Bg = Wb + (size_t)e * N * K + (size_t)(nt * BN) * K;

  f32x4 acc[4][4];
#pragma unroll
  for (int i = 0; i < 4; ++i)
#pragma unroll
    for (int j = 0; j < 4; ++j) acc[i][j] = (f32x4){0.f, 0.f, 0.f, 0.f};

  for (int kb = 0; kb < K / BK; ++kb) {
    // stage A tile: 128x64 bf16 = 16KB = 4 issues x 256 thr x 16B
#pragma unroll
    for (int i = 0; i < 4; ++i) {
      int el = i * 256 + tid;
      int r = el >> 3, c = (el & 7) << 3;
      gload_lds16(As + (size_t)(i * 256 + wave * 64) * 8,
                  Ag + (size_t)r * K + kb * BK + c);
    }
#pragma unroll
    for (int i = 0; i < 4; ++i) {
      int el = i * 256 + tid;
      int r = el >> 3, c = (el & 7) << 3;
      gload_lds16(Bs + (size_t)(i * 256 + wave * 64) * 8,
                  Bg + (size_t)r * K + kb * BK + c);
    }
    __syncthreads();
#pragma unroll
    for (int ks = 0; ks < 2; ++ks) {
      bf16x8 af[4], bfr[4];
#pragma unroll
      for (int mi = 0; mi < 4; ++mi)
        af[mi] = *(const bf16x8*)&As[(wm * 64 + mi * 16 + lr) * BK + ks * 32 + lk * 8];
#pragma unroll
      for (int ni = 0; ni < 4; ++ni)
        bfr[ni] = *(const bf16x8*)&Bs[(wn * 64 + ni * 16 + lr) * BK + ks * 32 + lk * 8];
#pragma unroll
      for (int mi = 0; mi < 4; ++mi)
#pragma unroll
        for (int ni = 0; ni < 4; ++ni)
          acc[mi][ni] = __builtin_amdgcn_mfma_f32_16x16x32_bf16(
              af[mi], bfr[ni], acc[mi][ni], 0, 0, 0);
    }
    __syncthreads();
  }

  // epilogue: C/D layout col = lane&15, row = (lane>>4)*4 + reg  [m89]
  size_t obase = (size_t)e * M_TOT * N;
  int row0 = mt * BM + wm * 64;
  int col0 = nt * BN + wn * 64;
#pragma unroll
  for (int mi = 0; mi < 4; ++mi)
#pragma unroll
    for (int ni = 0; ni < 4; ++ni) {
      int r0 = row0 + mi * 16 + lk * 4;
      int c = col0 + ni * 16 + lr;
      float* op = out + obase + (size_t)r0 * N + c;
#pragma unroll
      for (int t = 0; t < 4; ++t) op[(size_t)t * N] = acc[mi][ni][t];
    }
}

extern "C" void kernel_launch(void* const* d_in, const int* in_sizes, int n_in,
                              void* d_out, int out_size, void* d_ws, size_t ws_size,
                              hipStream_t stream) {
  const float* x = (const float*)d_in[0];        // [B][S][D] f32
  const float* theta = (const float*)d_in[1];    // [E][R] f32
  const float* proj_w = (const float*)d_in[2];   // [E][D][D] f32
  float* out = (float*)d_out;                    // [E][B][S][D] f32

  __hip_bfloat16* xb = (__hip_bfloat16*)d_ws;                       // 16 MB
  __hip_bfloat16* Wb = (__hip_bfloat16*)((char*)d_ws +
                        (size_t)M_TOT * D_ * sizeof(__hip_bfloat16));  // 4 MB

  hipLaunchKernelGGL(build_w_rot, dim3(E_), dim3(D_), 0, stream,
                     theta, proj_w, Wb);
  hipLaunchKernelGGL(conv_tail, dim3((E_ * D_ * D_) / 256), dim3(256), 0, stream,
                     proj_w, Wb);
  hipLaunchKernelGGL(conv_x, dim3((M_TOT * D_ / 4) / 256), dim3(256), 0, stream,
                     x, xb);
  hipLaunchKernelGGL(gemm_xw, dim3(E_ * (M_TOT / 128) * (D_ / 128)), dim3(256),
                     0, stream, xb, Wb, out);
}

// Round 2
// 147.348 us; speedup vs baseline: 1.2664x; 1.2664x over previous
//
#include <hip/hip_runtime.h>
#include <hip/hip_bf16.h>

#define E_ 8
#define B_ 8
#define S_ 2048
#define D_ 512
#define R_ 128
#define M_TOT (B_ * S_)   // 16384

typedef __attribute__((ext_vector_type(8))) short bf16x8;
typedef __attribute__((ext_vector_type(4))) float f32x4;

__device__ __forceinline__ void gload_lds16(void* lds, const void* g) {
  __builtin_amdgcn_global_load_lds(
      (const __attribute__((address_space(1))) void*)g,
      (__attribute__((address_space(3))) void*)lds, 16, 0, 0);
}

// ---------------------------------------------------------------------------
// Kernel 1: W[e] cols 0..128 = rotation-touched part of proj_w[e] @ Rm[e].
// All Givens planes are (0, k+1) -> per-row recurrence over k.
// LDS-chunked: coalesced loads of P[:,1+32c..+32), recurrence in LDS,
// coalesced bf16 stores. (Old version: stride-512 scalar reads, ~15us.)
// ---------------------------------------------------------------------------
__global__ __launch_bounds__(512) void build_w_rot(
    const float* __restrict__ theta, const float* __restrict__ pw,
    __hip_bfloat16* __restrict__ Wb) {
  int e = blockIdx.x;
  int t = threadIdx.x;  // 0..511 = row
  __shared__ float cs[R_], ss[R_];
  __shared__ float Pch[512][33];            // +1 pad: conflict-free
  __shared__ __hip_bfloat16 Wch[512][34];   // 17-dword stride: 2-way max
  if (t < R_) {
    float a = tanhf(theta[e * R_ + t]) * 0.1f;
    cs[t] = cosf(a);
    ss[t] = sinf(a);
  }
  const float* Pe = pw + (size_t)e * D_ * D_;
  __hip_bfloat16* We = Wb + (size_t)e * D_ * D_;
  float u = Pe[(size_t)t * D_];  // P[t][0]
  __syncthreads();
  for (int c = 0; c < 4; ++c) {
    for (int i = t; i < 512 * 32; i += 512) {
      int row = i >> 5, col = i & 31;
      Pch[row][col] = Pe[(size_t)row * D_ + 1 + 32 * c + col];
    }
    __syncthreads();
#pragma unroll
    for (int kk = 0; kk < 32; ++kk) {
      int k = 32 * c + kk;
      float pj = Pch[t][kk];
      Wch[t][kk] = __float2bfloat16(cs[k] * pj - ss[k] * u);
      u = cs[k] * u + ss[k] * pj;
    }
    __syncthreads();
    for (int i = t; i < 512 * 32; i += 512) {
      int row = i >> 5, col = i & 31;
      We[(size_t)row * D_ + 1 + 32 * c + col] = Wch[row][col];
    }
    __syncthreads();
  }
  We[(size_t)t * D_] = __float2bfloat16(u);
}

// ---------------------------------------------------------------------------
// Kernel 2: untouched columns d = 129..511 of W are proj_w columns. bf16 copy.
// ---------------------------------------------------------------------------
__global__ void conv_tail(const float* __restrict__ pw,
                          __hip_bfloat16* __restrict__ Wb) {
  int i = blockIdx.x * blockDim.x + threadIdx.x;  // over E*D*D
  int d = i & (D_ - 1);
  if (d > R_) Wb[i] = __float2bfloat16(pw[i]);
}

// ---------------------------------------------------------------------------
// Kernel 3: x f32 -> bf16, float4 vectorized.
// ---------------------------------------------------------------------------
__global__ void conv_x(const float* __restrict__ x,
                       __hip_bfloat16* __restrict__ xb) {
  int i = blockIdx.x * blockDim.x + threadIdx.x;
  float4 v = ((const float4*)x)[i];
  union { short4 s; __hip_bfloat16 h[4]; } u;
  u.h[0] = __float2bfloat16(v.x);
  u.h[1] = __float2bfloat16(v.y);
  u.h[2] = __float2bfloat16(v.z);
  u.h[3] = __float2bfloat16(v.w);
  ((short4*)xb)[i] = u.s;
}

// ---------------------------------------------------------------------------
// Kernel 4: out[e] = Xb @ Wb[e]^T  (NT GEMM). 256x256 tile, BK=32,
// 4-deep LDS ring (stage t+3 while computing t), counted vmcnt(8) (T3/T4),
// source-side XOR swizzle (T2), setprio around MFMA (T5), 8 waves (2Mx4N).
// ---------------------------------------------------------------------------
__global__ __launch_bounds__(512, 2) void gemm_xw(
    const __hip_bfloat16* __restrict__ Xb,   // [M_TOT][512]
    const __hip_bfloat16* __restrict__ Wb,   // [E][512][512] rows=o, cols=d
    float* __restrict__ out)                 // [E][M_TOT][512]
{
  constexpr int BM = 256, BN = 256, BK = 32;
  constexpr int KDIM = D_, NDIM = D_;
  constexpr int NT = KDIM / BK;  // 16
  __shared__ __align__(16) __hip_bfloat16 As[4][BM * BK];  // 64 KB
  __shared__ __align__(16) __hip_bfloat16 Bs[4][BN * BK];  // 64 KB

  // T1: bijective XCD-chunked swizzle, mt-major (A-panel reuse within XCD).
  int bx = blockIdx.x;                 // 1024 blocks, 1024%8==0
  int swz = (bx & 7) * 128 + (bx >> 3);
  int mt = swz >> 4;          // 0..63
  int e  = (swz >> 1) & 7;    // 0..7
  int nt = swz & 1;           // 0..1

  int tid = threadIdx.x;
  int wave = tid >> 6, lane = tid & 63;
  int lr = lane & 15, lk = lane >> 4;
  int wm = wave >> 2, wn = wave & 3;   // 2 x 4 waves, each owns 128x64 of C

  const __hip_bfloat16* Ag = Xb + (size_t)(mt * BM) * KDIM;
  const __hip_bfloat16* Bg = Wb + (size_t)e * NDIM * KDIM +
                             (size_t)(nt * BN) * KDIM;

  // staging geometry: wave covers 16 rows x 64B per issue; lane -> (row,slot)
  int srl = lane >> 2;                  // row within wave chunk, 0..15
  int scc = (lane & 3) ^ (srl & 3);     // T2: pre-swizzled global chunk

  f32x4 acc[8][4];
#pragma unroll
  for (int i = 0; i < 8; ++i)
#pragma unroll
    for (int j = 0; j < 4; ++j) acc[i][j] = (f32x4){0.f, 0.f, 0.f, 0.f};

  // prologue: stage K-tiles 0,1,2 (12 issues/wave)
#pragma unroll
  for (int p = 0; p < 3; ++p) {
#pragma unroll
    for (int i = 0; i < 2; ++i) {
      int row = i * 128 + wave * 16 + srl;
      gload_lds16(&As[p][(i * 128 + wave * 16) * BK],
                  Ag + (size_t)row * KDIM + p * BK + scc * 8);
      gload_lds16(&Bs[p][(i * 128 + wave * 16) * BK],
                  Bg + (size_t)row * KDIM + p * BK + scc * 8);
    }
  }

#pragma unroll 4
  for (int t = 0; t < NT; ++t) {
    // tile t resident once <=8 (tiles t+1,t+2) of my loads remain in flight
    asm volatile("s_waitcnt vmcnt(8)" ::: "memory");
    __builtin_amdgcn_s_barrier();
    if (t + 3 < NT) {  // stage tile t+3 into slot last read at iter t-1
      int tt = t + 3, slot = tt & 3;
#pragma unroll
      for (int i = 0; i < 2; ++i) {
        int row = i * 128 + wave * 16 + srl;
        gload_lds16(&As[slot][(i * 128 + wave * 16) * BK],
                    Ag + (size_t)row * KDIM + tt * BK + scc * 8);
        gload_lds16(&Bs[slot][(i * 128 + wave * 16) * BK],
                    Bg + (size_t)row * KDIM + tt * BK + scc * 8);
      }
    }
    const __hip_bfloat16* Asl = As[t & 3];
    const __hip_bfloat16* Bsl = Bs[t & 3];
    bf16x8 bfrag[4];
#pragma unroll
    for (int ni = 0; ni < 4; ++ni) {
      int row = wn * 64 + ni * 16 + lr;
      bfrag[ni] = *(const bf16x8*)&Bsl[row * BK + ((lk ^ (row & 3)) * 8)];
    }
    __builtin_amdgcn_s_setprio(1);
#pragma unroll
    for (int mi = 0; mi < 8; ++mi) {
      int row = wm * 128 + mi * 16 + lr;
      bf16x8 af = *(const bf16x8*)&Asl[row * BK + ((lk ^ (row & 3)) * 8)];
#pragma unroll
      for (int ni = 0; ni < 4; ++ni)
        acc[mi][ni] = __builtin_amdgcn_mfma_f32_16x16x32_bf16(
            af, bfrag[ni], acc[mi][ni], 0, 0, 0);
    }
    __builtin_amdgcn_s_setprio(0);
    __builtin_amdgcn_s_barrier();  // protects slot t&3 from iter t+1's stage
  }

  // epilogue: C/D layout col = lane&15, row = (lane>>4)*4 + reg  [m89]
  size_t obase = (size_t)e * M_TOT * NDIM;
  int row0 = mt * BM + wm * 128;
  int col0 = nt * BN + wn * 64;
#pragma unroll
  for (int mi = 0; mi < 8; ++mi)
#pragma unroll
    for (int ni = 0; ni < 4; ++ni) {
      int r0 = row0 + mi * 16 + lk * 4;
      int c = col0 + ni * 16 + lr;
      float* op = out + obase + (size_t)r0 * NDIM + c;
#pragma unroll
      for (int q = 0; q < 4; ++q) op[(size_t)q * NDIM] = acc[mi][ni][q];
    }
}

extern "C" void kernel_launch(void* const* d_in, const int* in_sizes, int n_in,
                              void* d_out, int out_size, void* d_ws, size_t ws_size,
                              hipStream_t stream) {
  const float* x = (const float*)d_in[0];        // [B][S][D] f32
  const float* theta = (const float*)d_in[1];    // [E][R] f32
  const float* proj_w = (const float*)d_in[2];   // [E][D][D] f32
  float* out = (float*)d_out;                    // [E][B][S][D] f32

  __hip_bfloat16* xb = (__hip_bfloat16*)d_ws;                          // 16 MB
  __hip_bfloat16* Wb = (__hip_bfloat16*)((char*)d_ws +
                        (size_t)M_TOT * D_ * sizeof(__hip_bfloat16));  // 4 MB

  hipLaunchKernelGGL(build_w_rot, dim3(E_), dim3(512), 0, stream,
                     theta, proj_w, Wb);
  hipLaunchKernelGGL(conv_tail, dim3((E_ * D_ * D_) / 256), dim3(256), 0, stream,
                     proj_w, Wb);
  hipLaunchKernelGGL(conv_x, dim3((M_TOT * D_ / 4) / 256), dim3(256), 0, stream,
                     x, xb);
  hipLaunchKernelGGL(gemm_xw, dim3(E_ * (M_TOT / 256) * (D_ / 256)), dim3(512),
                     0, stream, xb, Wb, out);
}